// Round 6
// baseline (191.513 us; speedup 1.0000x reference)
//
#include <hip/hip_runtime.h>
#include <math.h>

#define NB 2
#define NL 256
#define DM 512
#define NH 8
#define DQ 64

typedef float v2f __attribute__((ext_vector_type(2)));
typedef float v4f __attribute__((ext_vector_type(4)));

#if __has_builtin(__builtin_elementwise_fma)
__device__ __forceinline__ v2f fmav(v2f a, v2f b, v2f c) {
    return __builtin_elementwise_fma(a, b, c);
}
#else
__device__ __forceinline__ v2f fmav(v2f a, v2f b, v2f c) {
    v2f r; r.x = fmaf(a.x, b.x, c.x); r.y = fmaf(a.y, b.y, c.y); return r;
}
#endif
__device__ __forceinline__ v2f swapv(v2f a) {
    return __builtin_shufflevector(a, a, 1, 0);
}

// ---------------------------------------------------------------------------
// K1: QKV projection GEMM — RESTRUCTURED this round (same math order).
// 128 threads, tile 32M x 64N, 4x4 per thread. A staged [m][kk] (no
// transpose) and read float4-over-kk: LDS cost per 32 fma = 8 x b128
// (was ~2 b32 + 1 b128 per 8 fma) -> ~2.4x less LDS-pipe pressure.
// Accumulation per element: single chain, kk ascending (bit-identical).
// z==1 (k): TRANSPOSED (b,h,d,t). z==2 (v): computes u = (v+bias)@Win_h.
// ---------------------------------------------------------------------------
__global__ __launch_bounds__(128, 2) void qkv_gemm(
    const float* __restrict__ xq, const float* __restrict__ xk,
    const float* __restrict__ xv,
    const float* __restrict__ Wq, const float* __restrict__ Wk,
    const float* __restrict__ Wv,
    const float* __restrict__ bq, const float* __restrict__ bk,
    const float* __restrict__ bv,
    const float* __restrict__ Wre, const float* __restrict__ Wim,
    float* __restrict__ q, float* __restrict__ kT, float2* __restrict__ u)
{
    int z = blockIdx.z;
    const float* X = (z == 0) ? xq : (z == 1) ? xk : xv;
    const float* W = (z == 0) ? Wq : (z == 1) ? Wk : Wv;
    const float* bias = (z == 0) ? bq : (z == 1) ? bk : bv;

    __shared__ float As[32][36];   // [m][kk], 144B row stride (16B aligned)
    __shared__ float Bs[32][68];   // [kk][n]

    int tid = threadIdx.x;
    int tx = tid & 15, ty = tid >> 4;          // tx: n/4 (0..15), ty: m/4 (0..7)
    int m0 = blockIdx.y * 32, n0 = blockIdx.x * 64;

    // A staging: 2 float4/thread: rows (tid>>3), (tid>>3)+16; cols (tid&7)*4
    int arr = tid >> 3, ac4 = (tid & 7) * 4;
    const float* Aptr0 = X + (m0 + arr) * 512 + ac4;
    const float* Aptr1 = X + (m0 + arr + 16) * 512 + ac4;
    // B staging: 4 float4/thread: rows (tid>>4)+{0,8,16,24}; cols (tid&15)*4
    int brr = tid >> 4, bc4 = (tid & 15) * 4;
    const float* Bp0 = W + (brr +  0) * 512 + n0 + bc4;
    const float* Bp1 = W + (brr +  8) * 512 + n0 + bc4;
    const float* Bp2 = W + (brr + 16) * 512 + n0 + bc4;
    const float* Bp3 = W + (brr + 24) * 512 + n0 + bc4;

    float acc[4][4] = {};

    float4 aR0 = *(const float4*)(Aptr0);
    float4 aR1 = *(const float4*)(Aptr1);
    float4 bR0 = *(const float4*)(Bp0);
    float4 bR1 = *(const float4*)(Bp1);
    float4 bR2 = *(const float4*)(Bp2);
    float4 bR3 = *(const float4*)(Bp3);

    for (int k0 = 0; k0 < 512; k0 += 32) {
        *(float4*)&As[arr][ac4]       = aR0;
        *(float4*)&As[arr + 16][ac4]  = aR1;
        *(float4*)&Bs[brr][bc4]       = bR0;
        *(float4*)&Bs[brr +  8][bc4]  = bR1;
        *(float4*)&Bs[brr + 16][bc4]  = bR2;
        *(float4*)&Bs[brr + 24][bc4]  = bR3;
        __syncthreads();

        if (k0 + 32 < 512) {
            aR0 = *(const float4*)(Aptr0 + k0 + 32);
            aR1 = *(const float4*)(Aptr1 + k0 + 32);
            bR0 = *(const float4*)(Bp0 + (k0 + 32) * 512);
            bR1 = *(const float4*)(Bp1 + (k0 + 32) * 512);
            bR2 = *(const float4*)(Bp2 + (k0 + 32) * 512);
            bR3 = *(const float4*)(Bp3 + (k0 + 32) * 512);
        }

        #pragma unroll
        for (int kk4 = 0; kk4 < 32; kk4 += 4) {
            v4f a0 = *(const v4f*)&As[ty * 4 + 0][kk4];
            v4f a1 = *(const v4f*)&As[ty * 4 + 1][kk4];
            v4f a2 = *(const v4f*)&As[ty * 4 + 2][kk4];
            v4f a3 = *(const v4f*)&As[ty * 4 + 3][kk4];
            #pragma unroll
            for (int kc = 0; kc < 4; kc++) {
                v4f bb = *(const v4f*)&Bs[kk4 + kc][tx * 4];
                #pragma unroll
                for (int j = 0; j < 4; j++) {
                    acc[0][j] += a0[kc] * bb[j];
                    acc[1][j] += a1[kc] * bb[j];
                    acc[2][j] += a2[kc] * bb[j];
                    acc[3][j] += a3[kc] * bb[j];
                }
            }
        }
        __syncthreads();
    }

    if (z < 2) {
        float* O = (z == 0) ? q : kT;
        #pragma unroll
        for (int i = 0; i < 4; i++) {
            int m = m0 + ty * 4 + i;
            int b = m >> 8, l = m & 255;
            #pragma unroll
            for (int j = 0; j < 4; j++) {
                int n = n0 + tx * 4 + j;
                int h = n >> 6, d = n & 63;
                float val = acc[i][j] + bias[n];
                if (z == 1)
                    O[((b * NH + h) * DQ + d) * NL + l] = val;   // kT
                else
                    O[((b * NH + h) * NL + l) * DQ + d] = val;
            }
        }
    } else {
        int h = blockIdx.x;            // n-tile == head
        int b = m0 >> 8;
        #pragma unroll
        for (int i = 0; i < 4; i++)
            #pragma unroll
            for (int j = 0; j < 4; j++)
                Bs[ty * 4 + i][tx * 4 + j] = acc[i][j] + bias[n0 + tx * 4 + j];
        __syncthreads();

        float ur[4][4] = {}, ui[4][4] = {};
        const float* wr = Wre + h * 4096 + tx * 4;
        const float* wi = Wim + h * 4096 + tx * 4;
        #pragma unroll 4
        for (int d = 0; d < 64; d++) {
            float4 wre = *(const float4*)(wr + d * 64);
            float4 wim = *(const float4*)(wi + d * 64);
            float v0 = Bs[ty * 4 + 0][d];
            float v1 = Bs[ty * 4 + 1][d];
            float v2 = Bs[ty * 4 + 2][d];
            float v3 = Bs[ty * 4 + 3][d];
            ur[0][0] += v0 * wre.x; ur[0][1] += v0 * wre.y;
            ur[0][2] += v0 * wre.z; ur[0][3] += v0 * wre.w;
            ui[0][0] += v0 * wim.x; ui[0][1] += v0 * wim.y;
            ui[0][2] += v0 * wim.z; ui[0][3] += v0 * wim.w;
            ur[1][0] += v1 * wre.x; ur[1][1] += v1 * wre.y;
            ur[1][2] += v1 * wre.z; ur[1][3] += v1 * wre.w;
            ui[1][0] += v1 * wim.x; ui[1][1] += v1 * wim.y;
            ui[1][2] += v1 * wim.z; ui[1][3] += v1 * wim.w;
            ur[2][0] += v2 * wre.x; ur[2][1] += v2 * wre.y;
            ur[2][2] += v2 * wre.z; ur[2][3] += v2 * wre.w;
            ui[2][0] += v2 * wim.x; ui[2][1] += v2 * wim.y;
            ui[2][2] += v2 * wim.z; ui[2][3] += v2 * wim.w;
            ur[3][0] += v3 * wre.x; ur[3][1] += v3 * wre.y;
            ur[3][2] += v3 * wre.z; ur[3][3] += v3 * wre.w;
            ui[3][0] += v3 * wim.x; ui[3][1] += v3 * wim.y;
            ui[3][2] += v3 * wim.z; ui[3][3] += v3 * wim.w;
        }
        #pragma unroll
        for (int i = 0; i < 4; i++) {
            int l = (m0 & 255) + ty * 4 + i;
            float2* up = u + ((size_t)(b * NH + h) * NL + l) * DQ + tx * 4;
            #pragma unroll
            for (int j = 0; j < 4; j++)
                up[j] = make_float2(ur[i][j], ui[i][j]);
        }
    }
}

// ---------------------------------------------------------------------------
// K2: attn prologue + EUNN recurrence — VERBATIM R5 (passed, 70.9 us).
// ---------------------------------------------------------------------------
__device__ __forceinline__ float dpp_swap1(float x) {  // lane i <- lane i^1
    return __int_as_float(__builtin_amdgcn_mov_dpp(__float_as_int(x), 0xB1, 0xF, 0xF, true));
}
__device__ __forceinline__ float dpp_rol1(float x) {   // lane i <- lane (i+1)%64
    return __int_as_float(__builtin_amdgcn_mov_dpp(__float_as_int(x), 0x134, 0xF, 0xF, true));
}
__device__ __forceinline__ float dpp_ror1(float x) {   // lane i <- lane (i-1)%64
    return __int_as_float(__builtin_amdgcn_mov_dpp(__float_as_int(x), 0x13C, 0xF, 0xF, true));
}

__device__ __forceinline__ v2f mdr(v2f z, float bv) {  // modrelu, exact reference form
    float mm = z.x * z.x + z.y * z.y;
    float m = __builtin_amdgcn_sqrtf(mm);
    float sc = fmaxf(m + bv, 0.f) * __builtin_amdgcn_rcpf(m + 1e-5f);
    v2f s = {sc, sc};
    return z * s;
}

__global__ __launch_bounds__(256, 4) void rnn_kernel(
    const float* __restrict__ q, const float* __restrict__ kT,
    const float* __restrict__ mask, float* __restrict__ attn_o,
    const float2* __restrict__ u,
    const float* __restrict__ theta, const float* __restrict__ phi,
    const float* __restrict__ rnn_bias, float* __restrict__ rnn_out)
{
    int tid  = threadIdx.x;
    int wv   = tid >> 6;          // wave = one q row
    int lane = tid & 63;

    int blk = blockIdx.x;         // 1024: b(1) | h(3) | qg(6)
    int qg  = blk & 63;           // group of 4 q rows
    int h   = (blk >> 6) & 7;
    int b   = blk >> 9;

    __shared__ float qs[256];
    __shared__ float lg[4 * 260];
    __shared__ float redm[4], reds[4];
    __shared__ float arow[4 * 256];

    // ================= attn prologue (R1-passed, verbatim) =================
    float acc[4];
    {
        qs[tid] = q[((size_t)(b * NH + h) * NL + qg * 4) * DQ + tid];
        __syncthreads();

        const float* kp = kT + (size_t)((b * NH + h) * DQ) * NL + tid;
        #pragma unroll
        for (int j = 0; j < 4; j++) acc[j] = 0.f;
        #pragma unroll
        for (int d4 = 0; d4 < 16; d4++) {
            float kv0 = kp[(d4 * 4 + 0) * NL];
            float kv1 = kp[(d4 * 4 + 1) * NL];
            float kv2 = kp[(d4 * 4 + 2) * NL];
            float kv3 = kp[(d4 * 4 + 3) * NL];
            #pragma unroll
            for (int j = 0; j < 4; j++) {
                const float4 qv = *(const float4*)&qs[j * 64 + d4 * 4];
                acc[j] += qv.x * kv0 + qv.y * kv1 + qv.z * kv2 + qv.w * kv3;
            }
        }
        #pragma unroll
        for (int j = 0; j < 4; j++) {
            float mv = mask[(size_t)(b * NL + qg * 4 + j) * NL + tid];
            acc[j] = acc[j] * 0.125f - ((mv == 1.0f) ? INFINITY : mv);
            lg[j * 260 + tid] = acc[j];
        }
        __syncthreads();
        {
            int j = wv;   // one row per wave
            float v0 = lg[j * 260 + lane],       v1 = lg[j * 260 + 64 + lane];
            float v2 = lg[j * 260 + 128 + lane], v3 = lg[j * 260 + 192 + lane];
            float mx = fmaxf(fmaxf(v0, v1), fmaxf(v2, v3));
            #pragma unroll
            for (int o = 32; o; o >>= 1) mx = fmaxf(mx, __shfl_xor(mx, o, 64));
            float s = __expf(v0 - mx) + __expf(v1 - mx) +
                      __expf(v2 - mx) + __expf(v3 - mx);
            #pragma unroll
            for (int o = 32; o; o >>= 1) s += __shfl_xor(s, o, 64);
            if (lane == 0) { redm[j] = mx; reds[j] = s; }
        }
        __syncthreads();
        #pragma unroll
        for (int j = 0; j < 4; j++) {
            float p = __expf(acc[j] - redm[j]) * __builtin_amdgcn_rcpf(reds[j]);
            attn_o[((size_t)(b * NH + h) * NL + qg * 4 + j) * NL + tid] = p;
            arow[j * 256 + tid] = p;
        }
        __syncthreads();
    }

    // ================= EUNN recurrence (R4-passed body, verbatim) ==========
    int qi = qg * 4 + wv;
    int d = lane;
    bool odd = d & 1;

    const float* tb = theta + h * 64;    // (8,2,32): c=0 at [0..31], c=1 at [32..63]
    const float* pb = phi + h * 64;

    int i0 = d >> 1;
    float th0 = tb[i0], ph0 = pb[i0];
    float c0 = cosf(th0), s0 = sinf(th0);
    float W0r = (odd ? s0 : -s0) * cosf(ph0);
    float W0i = -s0 * sinf(ph0);

    int i1 = odd ? (d >> 1) : (((d + 62) & 63) >> 1);
    float th1 = tb[32 + i1], ph1 = pb[32 + i1];
    float c1 = cosf(th1), s1 = sinf(th1);
    float W1r = (odd ? -s1 : s1) * cosf(ph1);
    float W1i = -s1 * sinf(ph1);

    float biasv = rnn_bias[h * 64 + d];

    v2f c0v = {c0, c0}, c1v = {c1, c1};
    v2f W0rV = {W0r, W0r}, W0iN = {-W0i, W0i};
    v2f W1rV = {W1r, W1r}, W1iN = {-W1i, W1i};

    const float* arl = arow + wv * 256;                           // LDS, wave-uniform
    const float2* up = u + (size_t)((b * NH + h) * NL) * DQ + d;  // coalesced

    v2f e = {0.f, 0.f};

    #define RSTEP(a_t, uu) do {                                              \
        v2f atv = {(a_t), (a_t)};                                            \
        v2f uv = {(uu).x, (uu).y};                                           \
        v2f p0;                                                              \
        p0.x = dpp_swap1(e.x); p0.y = dpp_swap1(e.y);                        \
        v2f g = fmav(c0v, e, fmav(W0rV, p0, W0iN * swapv(p0)));              \
        v2f rl, rr;                                                          \
        rl.x = dpp_rol1(g.x); rl.y = dpp_rol1(g.y);                          \
        rr.x = dpp_ror1(g.x); rr.y = dpp_ror1(g.y);                          \
        v2f p1;                                                              \
        p1.x = odd ? rl.x : rr.x;                                            \
        p1.y = odd ? rl.y : rr.y;                                            \
        v2f z = fmav(c1v, g, fmav(W1rV, p1, fmav(W1iN, swapv(p1), atv * uv))); \
        e = mdr(z, biasv);                                                   \
    } while (0)

    // register double-buffer, 8-step groups; sched_barrier(0) pins the loads
    // ahead of the compute so counted vmcnt waits pipeline them.
    float2 U0[8], U1[8];
    float4 a0lo, a0hi, a1lo, a1hi;

    #pragma unroll
    for (int i = 0; i < 8; i++) U0[i] = up[i * 64];
    a0lo = *(const float4*)&arl[0];
    a0hi = *(const float4*)&arl[4];
    __builtin_amdgcn_sched_barrier(0);

    for (int k = 0; k < 16; k++) {            // 16 steps per iteration
        int t1 = k * 16 + 8;
        #pragma unroll
        for (int i = 0; i < 8; i++) U1[i] = up[(t1 + i) * 64];
        a1lo = *(const float4*)&arl[t1];
        a1hi = *(const float4*)&arl[t1 + 4];
        __builtin_amdgcn_sched_barrier(0);

        RSTEP(a0lo.x, U0[0]); RSTEP(a0lo.y, U0[1]);
        RSTEP(a0lo.z, U0[2]); RSTEP(a0lo.w, U0[3]);
        RSTEP(a0hi.x, U0[4]); RSTEP(a0hi.y, U0[5]);
        RSTEP(a0hi.z, U0[6]); RSTEP(a0hi.w, U0[7]);

        if (k < 15) {
            int t2 = k * 16 + 16;
            #pragma unroll
            for (int i = 0; i < 8; i++) U0[i] = up[(t2 + i) * 64];
            a0lo = *(const float4*)&arl[t2];
            a0hi = *(const float4*)&arl[t2 + 4];
        }
        __builtin_amdgcn_sched_barrier(0);

        RSTEP(a1lo.x, U1[0]); RSTEP(a1lo.y, U1[1]);
        RSTEP(a1lo.z, U1[2]); RSTEP(a1lo.w, U1[3]);
        RSTEP(a1hi.x, U1[4]); RSTEP(a1hi.y, U1[5]);
        RSTEP(a1hi.z, U1[6]); RSTEP(a1hi.w, U1[7]);
    }
    #undef RSTEP

    rnn_out[(size_t)(b * NL + qi) * DM + h * DQ + d] = e.x;
}

// ---------------------------------------------------------------------------
// K3: output projection — RESTRUCTURED this round (same math order).
// 128 threads, tile 16M x 64N, 2x4 per thread, A staged [m][kk] +
// float4-over-kk reads. Grid (8,32) = 256 blocks = 1 block/CU even.
// ---------------------------------------------------------------------------
__global__ __launch_bounds__(128, 2) void out_gemm(
    const float* __restrict__ A, const float* __restrict__ W,
    const float* __restrict__ bias, float* __restrict__ C)
{
    __shared__ float As[16][36];   // [m][kk]
    __shared__ float Bs[32][68];   // [kk][n]

    int tid = threadIdx.x;
    int tx = tid & 15, ty = tid >> 4;          // tx: n/4 (0..15), ty: m/2 (0..7)
    int m0 = blockIdx.y * 16, n0 = blockIdx.x * 64;

    // A staging: 1 float4/thread: row tid>>3 (0..15), cols (tid&7)*4
    int arr = tid >> 3, ac4 = (tid & 7) * 4;
    const float* Aptr = A + (m0 + arr) * 512 + ac4;
    // B staging: 4 float4/thread
    int brr = tid >> 4, bc4 = (tid & 15) * 4;
    const float* Bp0 = W + (brr +  0) * 512 + n0 + bc4;
    const float* Bp1 = W + (brr +  8) * 512 + n0 + bc4;
    const float* Bp2 = W + (brr + 16) * 512 + n0 + bc4;
    const float* Bp3 = W + (brr + 24) * 512 + n0 + bc4;

    float acc[2][4] = {};

    float4 aR  = *(const float4*)(Aptr);
    float4 bR0 = *(const float4*)(Bp0);
    float4 bR1 = *(const float4*)(Bp1);
    float4 bR2 = *(const float4*)(Bp2);
    float4 bR3 = *(const float4*)(Bp3);

    for (int k0 = 0; k0 < 512; k0 += 32) {
        *(float4*)&As[arr][ac4]      = aR;
        *(float4*)&Bs[brr][bc4]      = bR0;
        *(float4*)&Bs[brr +  8][bc4] = bR1;
        *(float4*)&Bs[brr + 16][bc4] = bR2;
        *(float4*)&Bs[brr + 24][bc4] = bR3;
        __syncthreads();

        if (k0 + 32 < 512) {
            aR  = *(const float4*)(Aptr + k0 + 32);
            bR0 = *(const float4*)(Bp0 + (k0 + 32) * 512);
            bR1 = *(const float4*)(Bp1 + (k0 + 32) * 512);
            bR2 = *(const float4*)(Bp2 + (k0 + 32) * 512);
            bR3 = *(const float4*)(Bp3 + (k0 + 32) * 512);
        }

        #pragma unroll
        for (int kk4 = 0; kk4 < 32; kk4 += 4) {
            v4f a0 = *(const v4f*)&As[ty * 2 + 0][kk4];
            v4f a1 = *(const v4f*)&As[ty * 2 + 1][kk4];
            #pragma unroll
            for (int kc = 0; kc < 4; kc++) {
                v4f bb = *(const v4f*)&Bs[kk4 + kc][tx * 4];
                #pragma unroll
                for (int j = 0; j < 4; j++) {
                    acc[0][j] += a0[kc] * bb[j];
                    acc[1][j] += a1[kc] * bb[j];
                }
            }
        }
        __syncthreads();
    }

    #pragma unroll
    for (int i = 0; i < 2; i++) {
        int m = m0 + ty * 2 + i;
        #pragma unroll
        for (int j = 0; j < 4; j++) {
            int n = n0 + tx * 4 + j;
            C[m * 512 + n] = acc[i][j] + bias[n];
        }
    }
}

// ---------------------------------------------------------------------------
extern "C" void kernel_launch(void* const* d_in, const int* in_sizes, int n_in,
                              void* d_out, int out_size, void* d_ws, size_t ws_size,
                              hipStream_t stream)
{
    const float* x_q  = (const float*)d_in[0];
    const float* x_k  = (const float*)d_in[1];
    const float* x_v  = (const float*)d_in[2];
    const float* mask = (const float*)d_in[3];
    const float* Wq   = (const float*)d_in[4];
    const float* bq   = (const float*)d_in[5];
    const float* Wk   = (const float*)d_in[6];
    const float* bk   = (const float*)d_in[7];
    const float* Wv   = (const float*)d_in[8];
    const float* bv   = (const float*)d_in[9];
    const float* Wo   = (const float*)d_in[10];
    const float* bo   = (const float*)d_in[11];
    const float* theta= (const float*)d_in[12];
    const float* phi  = (const float*)d_in[13];
    const float* Wre  = (const float*)d_in[14];
    const float* Wim  = (const float*)d_in[15];
    const float* rb   = (const float*)d_in[16];

    float* ws = (float*)d_ws;
    float*  q_ws    = ws;                       // 262144 f
    float*  kT_ws   = ws + 262144;              // 262144 f (b,h,d,t)
    float2* u_ws    = (float2*)(ws + 524288);   // 262144 float2
    float*  rnn_o   = ws + 1048576;             // 262144 f

    float* out_o  = (float*)d_out;              // (2,256,512)
    float* attn_o = out_o + NB * NL * DM;       // (2,8,256,256)

    qkv_gemm<<<dim3(8, 16, 3), 128, 0, stream>>>(
        x_q, x_k, x_v, Wq, Wk, Wv, bq, bk, bv, Wre, Wim,
        q_ws, kT_ws, u_ws);

    rnn_kernel<<<dim3(1024), 256, 0, stream>>>(
        q_ws, kT_ws, mask, attn_o, u_ws, theta, phi, rb, rnn_o);

    out_gemm<<<dim3(8, 32), 128, 0, stream>>>(rnn_o, Wo, bo, out_o);
}

// Round 8
// 177.623 us; speedup vs baseline: 1.0782x; 1.0782x over previous
//
#include <hip/hip_runtime.h>
#include <math.h>

#define NB 2
#define NL 256
#define DM 512
#define NH 8
#define DQ 64

typedef float v2f __attribute__((ext_vector_type(2)));

#if __has_builtin(__builtin_elementwise_fma)
__device__ __forceinline__ v2f fmav(v2f a, v2f b, v2f c) {
    return __builtin_elementwise_fma(a, b, c);
}
#else
__device__ __forceinline__ v2f fmav(v2f a, v2f b, v2f c) {
    v2f r; r.x = fmaf(a.x, b.x, c.x); r.y = fmaf(a.y, b.y, c.y); return r;
}
#endif
__device__ __forceinline__ v2f swapv(v2f a) {
    return __builtin_shufflevector(a, a, 1, 0);
}

// ---------------------------------------------------------------------------
// K1: QKV projection GEMM (R0-passed, verbatim). Register double-buffered.
// z==1 (k): TRANSPOSED (b,h,d,t). z==2 (v): computes u = (v+bias)@Win_h.
// ---------------------------------------------------------------------------
__global__ __launch_bounds__(256) void qkv_gemm(
    const float* __restrict__ xq, const float* __restrict__ xk,
    const float* __restrict__ xv,
    const float* __restrict__ Wq, const float* __restrict__ Wk,
    const float* __restrict__ Wv,
    const float* __restrict__ bq, const float* __restrict__ bk,
    const float* __restrict__ bv,
    const float* __restrict__ Wre, const float* __restrict__ Wim,
    float* __restrict__ q, float* __restrict__ kT, float2* __restrict__ u)
{
    int z = blockIdx.z;
    const float* X = (z == 0) ? xq : (z == 1) ? xk : xv;
    const float* W = (z == 0) ? Wq : (z == 1) ? Wk : Wv;
    const float* bias = (z == 0) ? bq : (z == 1) ? bk : bv;

    __shared__ float As[32][33];
    __shared__ float Bs[32][68];

    int tid = threadIdx.x;
    int tx = tid & 15, ty = tid >> 4;
    int m0 = blockIdx.y * 32, n0 = blockIdx.x * 64;

    int ar = tid >> 3, ac4 = (tid & 7) * 4;
    int br = tid >> 4, bc4 = (tid & 15) * 4;
    const float* Aptr = X + (m0 + ar) * 512 + ac4;
    const float* Bptr0 = W + br * 512 + n0 + bc4;
    const float* Bptr1 = W + (br + 16) * 512 + n0 + bc4;

    float acc[2][4] = {};

    float4 aR = *(const float4*)(Aptr);
    float4 bR0 = *(const float4*)(Bptr0);
    float4 bR1 = *(const float4*)(Bptr1);

    for (int k0 = 0; k0 < 512; k0 += 32) {
        As[ac4 + 0][ar] = aR.x; As[ac4 + 1][ar] = aR.y;
        As[ac4 + 2][ar] = aR.z; As[ac4 + 3][ar] = aR.w;
        *(float4*)&Bs[br][bc4] = bR0;
        *(float4*)&Bs[br + 16][bc4] = bR1;
        __syncthreads();

        if (k0 + 32 < 512) {
            aR  = *(const float4*)(Aptr + k0 + 32);
            bR0 = *(const float4*)(Bptr0 + (k0 + 32) * 512);
            bR1 = *(const float4*)(Bptr1 + (k0 + 32) * 512);
        }

        #pragma unroll
        for (int kk = 0; kk < 32; kk++) {
            float a0 = As[kk][ty * 2 + 0];
            float a1 = As[kk][ty * 2 + 1];
            float4 bb = *(const float4*)&Bs[kk][tx * 4];
            acc[0][0] += a0 * bb.x; acc[0][1] += a0 * bb.y;
            acc[0][2] += a0 * bb.z; acc[0][3] += a0 * bb.w;
            acc[1][0] += a1 * bb.x; acc[1][1] += a1 * bb.y;
            acc[1][2] += a1 * bb.z; acc[1][3] += a1 * bb.w;
        }
        __syncthreads();
    }

    if (z < 2) {
        float* O = (z == 0) ? q : kT;
        #pragma unroll
        for (int i = 0; i < 2; i++) {
            int m = m0 + ty * 2 + i;
            int b = m >> 8, l = m & 255;
            #pragma unroll
            for (int j = 0; j < 4; j++) {
                int n = n0 + tx * 4 + j;
                int h = n >> 6, d = n & 63;
                float val = acc[i][j] + bias[n];
                if (z == 1)
                    O[((b * NH + h) * DQ + d) * NL + l] = val;   // kT
                else
                    O[((b * NH + h) * NL + l) * DQ + d] = val;
            }
        }
    } else {
        int h = blockIdx.x;            // n-tile == head
        int b = m0 >> 8;
        #pragma unroll
        for (int i = 0; i < 2; i++)
            #pragma unroll
            for (int j = 0; j < 4; j++)
                Bs[ty * 2 + i][tx * 4 + j] = acc[i][j] + bias[n0 + tx * 4 + j];
        __syncthreads();

        int r0 = ty * 2, c4 = tx * 4;
        float ur[2][4] = {}, ui[2][4] = {};
        const float* wr = Wre + h * 4096 + c4;
        const float* wi = Wim + h * 4096 + c4;
        #pragma unroll 4
        for (int d = 0; d < 64; d++) {
            float v0 = Bs[r0][d];
            float v1 = Bs[r0 + 1][d];
            float4 wre = *(const float4*)(wr + d * 64);
            float4 wim = *(const float4*)(wi + d * 64);
            ur[0][0] += v0 * wre.x; ur[0][1] += v0 * wre.y;
            ur[0][2] += v0 * wre.z; ur[0][3] += v0 * wre.w;
            ui[0][0] += v0 * wim.x; ui[0][1] += v0 * wim.y;
            ui[0][2] += v0 * wim.z; ui[0][3] += v0 * wim.w;
            ur[1][0] += v1 * wre.x; ur[1][1] += v1 * wre.y;
            ur[1][2] += v1 * wre.z; ur[1][3] += v1 * wre.w;
            ui[1][0] += v1 * wim.x; ui[1][1] += v1 * wim.y;
            ui[1][2] += v1 * wim.z; ui[1][3] += v1 * wim.w;
        }
        #pragma unroll
        for (int i = 0; i < 2; i++) {
            int l = (m0 & 255) + r0 + i;
            float2* up = u + ((size_t)(b * NH + h) * NL + l) * DQ + c4;
            #pragma unroll
            for (int j = 0; j < 4; j++)
                up[j] = make_float2(ur[i][j], ui[i][j]);
        }
    }
}

// ---------------------------------------------------------------------------
// K2: attn softmax prologue + EUNN recurrence. R2-passed body (4 dims/lane,
// 16 lanes/row, 4 rows/wave, 64-thread blocks; 66.7 us measured) with TWO
// changes this round:
//   (1) __launch_bounds__(64, 1): min 1 wave/EU -> VGPR budget up to ~256 so
//       the Ua/Ub register double-buffer STAYS in registers (R2's VGPR=76
//       proved demotion; need ~150).
//   (2) sched_barrier(0) after each prefetch-load block (R5-proven) so the
//       scheduler cannot sink chunk loads into the serial chain; counted
//       vmcnt waits keep the next chunk's 8 loads in flight across ~800 cy
//       of compute.
// Math bodies verbatim -> bitwise-identical numerics.
// ---------------------------------------------------------------------------
__device__ __forceinline__ float dpp_row_ror1(float x) {   // lane i <- lane (i-1) mod 16
    return __int_as_float(__builtin_amdgcn_mov_dpp(__float_as_int(x), 0x121, 0xF, 0xF, true));
}
__device__ __forceinline__ float dpp_row_rol1(float x) {   // lane i <- lane (i+1) mod 16
    return __int_as_float(__builtin_amdgcn_mov_dpp(__float_as_int(x), 0x12F, 0xF, 0xF, true));
}

__device__ __forceinline__ v2f mdr(v2f z, float bv) {      // modrelu, exact reference form
    float mm = z.x * z.x + z.y * z.y;
    float m = __builtin_amdgcn_sqrtf(mm);
    float sc = fmaxf(m + bv, 0.f) * __builtin_amdgcn_rcpf(m + 1e-5f);
    v2f s = {sc, sc};
    return z * s;
}

__global__ __launch_bounds__(64, 1) void rnn_kernel(
    const float* __restrict__ q, const float* __restrict__ kT,
    const float* __restrict__ mask, float* __restrict__ attn_o,
    const float2* __restrict__ u,
    const float* __restrict__ theta, const float* __restrict__ phi,
    const float* __restrict__ rnn_bias, float* __restrict__ rnn_out)
{
    int lane = threadIdx.x;       // block = 1 wave
    int blk = blockIdx.x;         // 1024 blocks: b(1) | h(3) | qg(6)
    int qg = blk & 63;            // group of 4 q rows
    int h  = (blk >> 6) & 7;
    int b  = blk >> 9;

    int row = lane >> 4;          // q-row within group (0..3)
    int p   = lane & 15;          // within-row lane; owns dims 4p..4p+3

    __shared__ float qs[4][68];       // +4 float row skew -> bank-spread
    __shared__ float arow[4][260];

    // ---------------- load q rows (4 x 64) ----------------
    {
        const float4* qsrc = (const float4*)(q + ((size_t)(b * NH + h) * NL + qg * 4) * DQ);
        float4 f4 = qsrc[lane];
        *(float4*)&qs[lane >> 4][(lane & 15) * 4] = f4;
    }
    __syncthreads();

    // ---------------- QK^T + softmax (keys: lane + 64*kk) ----------------
    float l[4][4];
    {
        const float* kp = kT + (size_t)((b * NH + h) * DQ) * NL + lane;
        float acc[4][4] = {};
        #pragma unroll
        for (int d4 = 0; d4 < 16; d4++) {
            float kv[4][4];
            #pragma unroll
            for (int kk = 0; kk < 4; kk++)
                #pragma unroll
                for (int i = 0; i < 4; i++)
                    kv[kk][i] = kp[(size_t)(d4 * 4 + i) * NL + kk * 64];
            #pragma unroll
            for (int r = 0; r < 4; r++) {
                float4 qv = *(const float4*)&qs[r][d4 * 4];
                #pragma unroll
                for (int kk = 0; kk < 4; kk++)
                    acc[r][kk] += qv.x * kv[kk][0] + qv.y * kv[kk][1]
                                + qv.z * kv[kk][2] + qv.w * kv[kk][3];
            }
        }
        #pragma unroll
        for (int r = 0; r < 4; r++)
            #pragma unroll
            for (int kk = 0; kk < 4; kk++) {
                float mv = mask[(size_t)(b * NL + qg * 4 + r) * NL + lane + kk * 64];
                l[r][kk] = acc[r][kk] * 0.125f - ((mv == 1.0f) ? INFINITY : mv);
            }
        #pragma unroll
        for (int r = 0; r < 4; r++) {
            float mx = fmaxf(fmaxf(l[r][0], l[r][1]), fmaxf(l[r][2], l[r][3]));
            #pragma unroll
            for (int o = 32; o; o >>= 1) mx = fmaxf(mx, __shfl_xor(mx, o, 64));
            float s = __expf(l[r][0] - mx) + __expf(l[r][1] - mx)
                    + __expf(l[r][2] - mx) + __expf(l[r][3] - mx);
            #pragma unroll
            for (int o = 32; o; o >>= 1) s += __shfl_xor(s, o, 64);
            float rs = __builtin_amdgcn_rcpf(s);
            #pragma unroll
            for (int kk = 0; kk < 4; kk++) {
                float pv = __expf(l[r][kk] - mx) * rs;
                attn_o[((size_t)(b * NH + h) * NL + qg * 4 + r) * NL + lane + kk * 64] = pv;
                arow[r][lane + kk * 64] = pv;
            }
        }
    }
    __syncthreads();

    // ---------------- EUNN recurrence (4 dims/lane) ----------------
    const float* tb = theta + h * 64;     // (8,2,32): c=0 at [0..31], c=1 at [32..63]
    const float* pb = phi + h * 64;

    // stage-0 pairs: A = pair 2p (dims 4p,4p+1), B = pair 2p+1 (dims 4p+2,4p+3)
    float thA = tb[2 * p], phA = pb[2 * p];
    float cA = cosf(thA), sA = sinf(thA), cpA = cosf(phA), spA = sinf(phA);
    float thB = tb[2 * p + 1], phB = pb[2 * p + 1];
    float cB = cosf(thB), sB = sinf(thB), cpB = cosf(phB), spB = sinf(phB);

    // W coeff helper: given (Wr, Wi): WrV = {Wr,Wr}, WiN = {-Wi, Wi}
    #define MKC(nm, Wr, Wi) v2f nm##rV = {(Wr), (Wr)}; v2f nm##iN = {-(Wi), (Wi)}
    MKC(WAa, -sA * cpA, -sA * spA);   // even member of pair A
    MKC(WAb,  sA * cpA, -sA * spA);   // odd member of pair A
    MKC(WBa, -sB * cpB, -sB * spB);
    MKC(WBb,  sB * cpB, -sB * spB);
    v2f cAv = {cA, cA}, cBv = {cB, cB};

    // stage-1 pair indices: j=0 -> iL=(2p+31)&31 ("b" pos); j=1,2 -> iM=2p; j=3 -> iR=2p+1
    int iL = (2 * p + 31) & 31;
    float thL = tb[32 + iL], phL = pb[32 + iL];
    float cL = cosf(thL), sL = sinf(thL);
    MKC(W1L,  sL * cosf(phL), -sL * sinf(phL));   // j=0 even "b"
    float thM = tb[32 + 2 * p], phM = pb[32 + 2 * p];
    float cM = cosf(thM), sM = sinf(thM), cpM = cosf(phM), spM = sinf(phM);
    MKC(W1M, -sM * cpM, -sM * spM);               // j=1 odd "a"
    MKC(W2M,  sM * cpM, -sM * spM);               // j=2 even "b"
    float thR = tb[32 + 2 * p + 1], phR = pb[32 + 2 * p + 1];
    float cR = cosf(thR), sR = sinf(thR);
    MKC(W1R, -sR * cosf(phR), -sR * sinf(phR));   // j=3 odd "a"
    v2f cLv = {cL, cL}, cMv = {cM, cM}, cRv = {cR, cR};
    #undef MKC

    float4 bias4 = *(const float4*)&rnn_bias[h * 64 + 4 * p];

    v2f e0 = {0.f, 0.f}, e1 = {0.f, 0.f}, e2 = {0.f, 0.f}, e3 = {0.f, 0.f};

    #define STEP(a_t, uA, uB) do {                                           \
        v2f atv = {(a_t), (a_t)};                                            \
        v2f u0 = {(uA).x, (uA).y}, u1 = {(uA).z, (uA).w};                    \
        v2f u2 = {(uB).x, (uB).y}, u3 = {(uB).z, (uB).w};                    \
        v2f g0 = fmav(cAv, e0, fmav(WAarV, e1, WAaiN * swapv(e1)));          \
        v2f g1 = fmav(cAv, e1, fmav(WAbrV, e0, WAbiN * swapv(e0)));          \
        v2f g2 = fmav(cBv, e2, fmav(WBarV, e3, WBaiN * swapv(e3)));          \
        v2f g3 = fmav(cBv, e3, fmav(WBbrV, e2, WBbiN * swapv(e2)));          \
        v2f gl, gr;                                                          \
        gl.x = dpp_row_ror1(g3.x); gl.y = dpp_row_ror1(g3.y);                \
        gr.x = dpp_row_rol1(g0.x); gr.y = dpp_row_rol1(g0.y);                \
        v2f z0 = fmav(cLv, g0, fmav(W1LrV, gl, fmav(W1LiN, swapv(gl), atv * u0))); \
        v2f z1 = fmav(cMv, g1, fmav(W1MrV, g2, fmav(W1MiN, swapv(g2), atv * u1))); \
        v2f z2 = fmav(cMv, g2, fmav(W2MrV, g1, fmav(W2MiN, swapv(g1), atv * u2))); \
        v2f z3 = fmav(cRv, g3, fmav(W1RrV, gr, fmav(W1RiN, swapv(gr), atv * u3))); \
        e0 = mdr(z0, bias4.x); e1 = mdr(z1, bias4.y);                        \
        e2 = mdr(z2, bias4.z); e3 = mdr(z3, bias4.w);                        \
    } while (0)

    // u stream: lane reads dims 4p..4p+3 at each t -> two float4 per t.
    const float4* up4 = (const float4*)(u + (size_t)((b * NH + h) * NL) * DQ) + 2 * p;

    // double-buffered chunks of 4 timesteps: 8 x dwordx4 + 1 x b128 per chunk
    float4 Ua[8], Ub[8];
    float4 aa, ab;
    #pragma unroll
    for (int i = 0; i < 8; i++) Ua[i] = up4[(i >> 1) * 32 + (i & 1)];
    aa = *(const float4*)&arow[row][0];
    __builtin_amdgcn_sched_barrier(0);

    for (int c = 0; c < 64; c += 2) {
        // prefetch chunk c+1 (always exists)
        const float4* upn = up4 + (c + 1) * 128;
        #pragma unroll
        for (int i = 0; i < 8; i++) Ub[i] = upn[(i >> 1) * 32 + (i & 1)];
        ab = *(const float4*)&arow[row][(c + 1) * 4];
        __builtin_amdgcn_sched_barrier(0);

        STEP(aa.x, Ua[0], Ua[1]);
        STEP(aa.y, Ua[2], Ua[3]);
        STEP(aa.z, Ua[4], Ua[5]);
        STEP(aa.w, Ua[6], Ua[7]);

        // prefetch chunk c+2 (guarded; stale regs unused on last trip)
        if (c + 2 < 64) {
            const float4* upn2 = up4 + (c + 2) * 128;
            #pragma unroll
            for (int i = 0; i < 8; i++) Ua[i] = upn2[(i >> 1) * 32 + (i & 1)];
            aa = *(const float4*)&arow[row][(c + 2) * 4];
        }
        __builtin_amdgcn_sched_barrier(0);

        STEP(ab.x, Ub[0], Ub[1]);
        STEP(ab.y, Ub[2], Ub[3]);
        STEP(ab.z, Ub[4], Ub[5]);
        STEP(ab.w, Ub[6], Ub[7]);
    }
    #undef STEP

    int qi = qg * 4 + row;
    float4 o4 = {e0.x, e1.x, e2.x, e3.x};
    *(float4*)&rnn_out[(size_t)(b * NL + qi) * DM + h * DQ + 4 * p] = o4;
}

// ---------------------------------------------------------------------------
// K3: output projection (R0-passed, verbatim). Register double-buffered.
// ---------------------------------------------------------------------------
__global__ __launch_bounds__(256) void out_gemm(
    const float* __restrict__ A, const float* __restrict__ W,
    const float* __restrict__ bias, float* __restrict__ C)
{
    __shared__ float As[32][17];
    __shared__ float Bs[32][68];

    int tid = threadIdx.x;
    int tx = tid & 15, ty = tid >> 4;
    int m0 = blockIdx.y * 16, n0 = blockIdx.x * 64;

    int ar = tid >> 4, ac2 = (tid & 15) * 2;
    int br = tid >> 4, bc4 = (tid & 15) * 4;
    const float* Aptr = A + (m0 + ar) * 512 + ac2;
    const float* Bptr0 = W + br * 512 + n0 + bc4;
    const float* Bptr1 = W + (br + 16) * 512 + n0 + bc4;

    float acc[4] = {};

    float2 aR = *(const float2*)(Aptr);
    float4 bR0 = *(const float4*)(Bptr0);
    float4 bR1 = *(const float4*)(Bptr1);

    for (int k0 = 0; k0 < 512; k0 += 32) {
        As[ac2 + 0][ar] = aR.x; As[ac2 + 1][ar] = aR.y;
        *(float4*)&Bs[br][bc4] = bR0;
        *(float4*)&Bs[br + 16][bc4] = bR1;
        __syncthreads();

        if (k0 + 32 < 512) {
            aR  = *(const float2*)(Aptr + k0 + 32);
            bR0 = *(const float4*)(Bptr0 + (k0 + 32) * 512);
            bR1 = *(const float4*)(Bptr1 + (k0 + 32) * 512);
        }

        #pragma unroll
        for (int kk = 0; kk < 32; kk++) {
            float a = As[kk][ty];
            float4 bb = *(const float4*)&Bs[kk][tx * 4];
            acc[0] += a * bb.x; acc[1] += a * bb.y;
            acc[2] += a * bb.z; acc[3] += a * bb.w;
        }
        __syncthreads();
    }

    int m = m0 + ty;
    #pragma unroll
    for (int j = 0; j < 4; j++) {
        int n = n0 + tx * 4 + j;
        C[m * 512 + n] = acc[j] + bias[n];
    }
}

// ---------------------------------------------------------------------------
extern "C" void kernel_launch(void* const* d_in, const int* in_sizes, int n_in,
                              void* d_out, int out_size, void* d_ws, size_t ws_size,
                              hipStream_t stream)
{
    const float* x_q  = (const float*)d_in[0];
    const float* x_k  = (const float*)d_in[1];
    const float* x_v  = (const float*)d_in[2];
    const float* mask = (const float*)d_in[3];
    const float* Wq   = (const float*)d_in[4];
    const float* bq   = (const float*)d_in[5];
    const float* Wk   = (const float*)d_in[6];
    const float* bk   = (const float*)d_in[7];
    const float* Wv   = (const float*)d_in[8];
    const float* bv   = (const float*)d_in[9];
    const float* Wo   = (const float*)d_in[10];
    const float* bo   = (const float*)d_in[11];
    const float* theta= (const float*)d_in[12];
    const float* phi  = (const float*)d_in[13];
    const float* Wre  = (const float*)d_in[14];
    const float* Wim  = (const float*)d_in[15];
    const float* rb   = (const float*)d_in[16];

    float* ws = (float*)d_ws;
    float*  q_ws    = ws;                       // 262144 f
    float*  kT_ws   = ws + 262144;              // 262144 f (b,h,d,t)
    float2* u_ws    = (float2*)(ws + 524288);   // 262144 float2
    float*  rnn_o   = ws + 1048576;              // 262144 f

    float* out_o  = (float*)d_out;              // (2,256,512)
    float* attn_o = out_o + NB * NL * DM;       // (2,8,256,256)

    qkv_gemm<<<dim3(8, 16, 3), 256, 0, stream>>>(
        x_q, x_k, x_v, Wq, Wk, Wv, bq, bk, bv, Wre, Wim,
        q_ws, kT_ws, u_ws);

    rnn_kernel<<<dim3(1024), 64, 0, stream>>>(
        q_ws, kT_ws, mask, attn_o, u_ws, theta, phi, rb, rnn_o);

    out_gemm<<<dim3(8, 32), 256, 0, stream>>>(rnn_o, Wo, bo, out_o);
}